// Round 10
// baseline (695.849 us; speedup 1.0000x reference)
//
#include <hip/hip_runtime.h>
#include <stdint.h>

#define T_LEN 2048
#define B_TOT 64
#define N_TAG 128

typedef __attribute__((ext_vector_type(4))) float f32x4;
typedef __attribute__((ext_vector_type(4))) uint32_t u32x4;
typedef __attribute__((ext_vector_type(2))) uint32_t u32x2;

template <int S>
struct IC {
  static constexpr int value = S;
};

// pack two fp32 -> dword of two bf16 (round-half-up); elem0 in low half
__device__ __forceinline__ uint32_t pack2_bf16(float a, float b) {
  uint32_t ua = __float_as_uint(a) + 0x8000u;
  uint32_t ub = __float_as_uint(b) + 0x8000u;
  return __builtin_amdgcn_perm(ua, ub, 0x03020706u);
}
__device__ __forceinline__ float bf_lo(uint32_t w) {
  return __uint_as_float(w << 16);
}
__device__ __forceinline__ float bf_hi(uint32_t w) {
  return __uint_as_float(w & 0xffff0000u);
}
// pack 4 fp32 -> 4 fp8 e4m3 (OCP), bytes 0..3 = a,b,c,d
__device__ __forceinline__ uint32_t pack4_fp8(float a, float b, float c,
                                              float d) {
  int v = __builtin_amdgcn_cvt_pk_fp8_f32(a, b, 0, false);
  v = __builtin_amdgcn_cvt_pk_fp8_f32(c, d, v, true);
  return (uint32_t)v;
}
// pack 4 fp32 -> 4 bf8 e5m2 (OCP), bytes 0..3 = a,b,c,d
__device__ __forceinline__ uint32_t pack4_bf8(float a, float b, float c,
                                              float d) {
  int v = __builtin_amdgcn_cvt_pk_bf8_f32(a, b, 0, false);
  v = __builtin_amdgcn_cvt_pk_bf8_f32(c, d, v, true);
  return (uint32_t)v;
}

// prepass: ws[t][b][i] = bf16(exp(em[b][t][i])), i-pairs packed in u32
__global__ __launch_bounds__(256) void eem_prepass(const float* __restrict__ em,
                                                   uint32_t* __restrict__ ws) {
  const int tid = blockIdx.x * blockDim.x + threadIdx.x;  // 0 .. 2^21-1
  const int b = tid >> 15;
  const int rem = tid & 32767;
  const int t = rem >> 4;
  const int kk = rem & 15;  // 8 floats per thread
  const float4* src =
      (const float4*)(em + ((size_t)b * T_LEN + t) * N_TAG + kk * 8);
  const float4 p0 = src[0];
  const float4 p1 = src[1];
  u32x4 o;
  o[0] = pack2_bf16(__expf(p0.x), __expf(p0.y));
  o[1] = pack2_bf16(__expf(p0.z), __expf(p0.w));
  o[2] = pack2_bf16(__expf(p1.x), __expf(p1.y));
  o[3] = pack2_bf16(__expf(p1.z), __expf(p1.w));
  *(u32x4*)(ws + ((size_t)t * B_TOT + b) * (N_TAG / 2) + kk * 4) = o;
}

// 4 blocks x 512 threads (8 waves), 16 batches/block, 2 waves/SIMD.
// State = bf8 e5m2 (wide range), E = fp8 e4m3, via mfma_f32_16x16x32_fp8_bf8
// (bf16 rate, half the LDS bytes of bf16): per-wave state read = 4x
// ds_read_b64, exchange write = 1x b32 (stride-2 banks -> 2-way = free).
// A rows permuted per wave (j = (w>>1)*32 + (m>>2)*8 + (w&1)*4 + (m&3)) so
// the f32x4 D output IS dword (w&1) of fragment (w>>1) of next step's B
// operand (consistent for any within-lane byte->k map shared by A and B).
// Per-step rescale, DAMPED controller: D = (probe_e >> 1) + 3 applied with a
// 1-step lag -> closed loop z^2 = z - 1/2 (|z|=0.707, no R9 oscillation
// blowup). Probe exponent clamped +-40 (scale can never overflow), state
// clamped at 16384 before the saturating bf8 cvt (no inf/NaN reachable).
__global__ __launch_bounds__(512, 2) void crf_fwd_kernel(
    const float* __restrict__ em, const int* __restrict__ lens,
    const float* __restrict__ trans, const float* __restrict__ head,
    const float* __restrict__ last, const uint32_t* __restrict__ eem,
    float* __restrict__ out) {
  const int lane = threadIdx.x & 63;
  const int w = threadIdx.x >> 6;  // 0..7
  const int f = w >> 1;            // owned fragment (k-tile it produces)
  const int h = w & 1;             // dword within fragment
  const int c = lane & 15;         // batch-in-tile
  const int q = lane >> 4;
  const int bg = (int)blockIdx.x * 16 + c;
  const int jbase = f * 32 + q * 8 + h * 4;  // lane's 4 j's: jbase + r

  __shared__ uint32_t x_lds[2][4][64][2];  // [pingpong][frag][lane][dword]
  __shared__ int k_lds[16];                // per-batch scale exponent D
  __shared__ float cap_lds[8][16];

  // A fragments (fp8 e4m3): lane row m=c, byte p -> k=kt*32+q*8+p,
  // value = exp(trans[k][jA]), jA = f*32 + (c>>2)*8 + h*4 + (c&3)
  u32x2 efrag[4];
  {
    const int jA = f * 32 + (c >> 2) * 8 + h * 4 + (c & 3);
#pragma unroll
    for (int kt = 0; kt < 4; ++kt) {
      float ev[8];
#pragma unroll
      for (int p = 0; p < 8; ++p)
        ev[p] = __expf(trans[(kt * 32 + q * 8 + p) * N_TAG + jA]);
      u32x2 wd;
      wd[0] = pack4_fp8(ev[0], ev[1], ev[2], ev[3]);
      wd[1] = pack4_fp8(ev[4], ev[5], ev[6], ev[7]);
      efrag[kt] = wd;
    }
  }

  float lastx[4];
#pragma unroll
  for (int r = 0; r < 4; ++r) lastx[r] = __expf(last[jbase + r]);

  const int len = lens[bg];
  float L = 0.f, Lcap = 0.f;

  // initial state: S0[b][i] = bf8(e^{head_i + em[b][0][i]}), i = jbase + r
  const float* emb = em + (size_t)bg * T_LEN * N_TAG;
  float v0[4];
#pragma unroll
  for (int r = 0; r < 4; ++r) v0[r] = __expf(head[jbase + r] + emb[jbase + r]);
  x_lds[0][f][lane][h] = pack4_bf8(v0[0], v0[1], v0[2], v0[3]);
  if (w == 0 && lane < 16) k_lds[lane] = 3;  // initial D
  if (len == 1) {  // edge (setup guarantees len>=1024; keep correct)
    float s = v0[0] * lastx[0] + v0[1] * lastx[1] + v0[2] * lastx[2] +
              v0[3] * lastx[3];
    s += __shfl_xor(s, 16);
    s += __shfl_xor(s, 32);
    if (q == 0) cap_lds[w][c] = s;
  }
  __syncthreads();
  if (len == 1 && w == 0 && lane < 16) {
    float s = 0.f;
#pragma unroll
    for (int u = 0; u < 8; ++u) s += cap_lds[u][c];
    out[bg] = __logf(s);
  }

  // eem prefetch: slot t&3 holds row t (this lane's 4 j's = u32x2 of bf16)
  const size_t eoff = (size_t)bg * 64 + f * 16 + q * 4 + h * 2;
  u32x2 eslot[4];
  auto issue_eem = [&](auto sc, int row) {
    constexpr int S = decltype(sc)::value;
    eslot[S] = *(const u32x2*)(eem + (size_t)row * 4096 + eoff);
  };
  issue_eem(IC<1>{}, 1);
  issue_eem(IC<2>{}, 2);
  issue_eem(IC<3>{}, 3);

  const f32x4 vzero = {0.f, 0.f, 0.f, 0.f};

  auto step = [&](auto slotc, int t) {
    constexpr int SLOT = decltype(slotc)::value;
    constexpr int RP = (SLOT + 1) & 1;  // read buffer (state of t-1)
    constexpr int WP = SLOT & 1;        // write buffer
    // prefetch first (vmem issue before LDS dependencies)
    {
      int row = t + 3;
      if (row > T_LEN - 1) row = T_LEN - 1;
      issue_eem(IC<(SLOT + 3) & 3>{}, row);
    }
    const int D = k_lds[c];  // scale exponent (from last step's probe)
    // B fragments: 4x ds_read_b64 (bf8 state, full k=128)
    u32x2 bfr[4];
#pragma unroll
    for (int kt = 0; kt < 4; ++kt)
      bfr[kt] = *(const u32x2*)&x_lds[RP][kt][lane][0];
    // unpack eem, fold per-step rescale 2^-D (D in [-17,23] by construction)
    const u32x2 ev = eslot[SLOT];
    float ff[4];
    ff[0] = bf_lo(ev[0]);
    ff[1] = bf_hi(ev[0]);
    ff[2] = bf_lo(ev[1]);
    ff[3] = bf_hi(ev[1]);
    const float sc = __uint_as_float((uint32_t)(127 - D) << 23);
#pragma unroll
    for (int r = 0; r < 4; ++r) ff[r] *= sc;
    L += (float)D * 0.6931471805599453f;
    // fp8(A=E) x bf8(B=state) MFMA, two 2-deep chains
    f32x4 accA = __builtin_amdgcn_mfma_f32_16x16x32_fp8_bf8(
        __builtin_bit_cast(long, efrag[0]), __builtin_bit_cast(long, bfr[0]),
        vzero, 0, 0, 0);
    f32x4 accB = __builtin_amdgcn_mfma_f32_16x16x32_fp8_bf8(
        __builtin_bit_cast(long, efrag[2]), __builtin_bit_cast(long, bfr[2]),
        vzero, 0, 0, 0);
    accA = __builtin_amdgcn_mfma_f32_16x16x32_fp8_bf8(
        __builtin_bit_cast(long, efrag[1]), __builtin_bit_cast(long, bfr[1]),
        accA, 0, 0, 0);
    accB = __builtin_amdgcn_mfma_f32_16x16x32_fp8_bf8(
        __builtin_bit_cast(long, efrag[3]), __builtin_bit_cast(long, bfr[3]),
        accB, 0, 0, 0);
    const f32x4 acc = accA + accB;
    // next state values (pre-clamp reused for capture)
    float st[4];
#pragma unroll
    for (int r = 0; r < 4; ++r) st[r] = acc[r] * ff[r];
    // capture: out_b = log(sum_j acc*eem*e^{last}) + L (this lane's 4 j's)
    if (t == len - 1) {
      float s = st[0] * lastx[0] + st[1] * lastx[1] + st[2] * lastx[2] +
                st[3] * lastx[3];
      s += __shfl_xor(s, 16);
      s += __shfl_xor(s, 32);
      if (q == 0) cap_lds[w][c] = s;
      Lcap = L;
    }
    // damped probe of j=0: wave 0, lanes 0-15 (q=0,r=0) hold alpha[0][c]
    if (w == 0 && lane < 16) {
      int e = (int)(__float_as_uint(acc[0]) >> 23) - 127;
      e = e < -40 ? -40 : (e > 40 ? 40 : e);
      k_lds[c] = (e >> 1) + 3;  // half-gain -> z^2 = z - 1/2, damped
    }
    // clamp (bf8-safe) and pack -- lane-local placement into B layout
#pragma unroll
    for (int r = 0; r < 4; ++r) st[r] = fminf(st[r], 16384.f);
    x_lds[WP][f][lane][h] = pack4_bf8(st[0], st[1], st[2], st[3]);
    __syncthreads();
    if (t == len - 1 && w == 0 && lane < 16) {
      float s = 0.f;
#pragma unroll
      for (int u = 0; u < 8; ++u) s += cap_lds[u][c];
      out[bg] = __logf(s) + Lcap;
    }
  };

  int t = 1;
#pragma unroll 1
  for (int it = 0; it < 511; ++it) {  // t = 1 .. 2044
    step(IC<1>{}, t);
    step(IC<2>{}, t + 1);
    step(IC<3>{}, t + 2);
    step(IC<0>{}, t + 3);
    t += 4;
  }
  step(IC<1>{}, t);      // 2045
  step(IC<2>{}, t + 1);  // 2046
  step(IC<3>{}, t + 2);  // 2047
}

extern "C" void kernel_launch(void* const* d_in, const int* in_sizes, int n_in,
                              void* d_out, int out_size, void* d_ws,
                              size_t ws_size, hipStream_t stream) {
  const float* em = (const float*)d_in[0];
  const int* lens = (const int*)d_in[1];
  const float* trans = (const float*)d_in[2];
  const float* head = (const float*)d_in[3];
  const float* last = (const float*)d_in[4];
  float* out = (float*)d_out;
  uint32_t* ws = (uint32_t*)d_ws;  // 2048*64*128 bf16 = 32 MiB

  eem_prepass<<<8192, 256, 0, stream>>>(em, ws);
  crf_fwd_kernel<<<4, 512, 0, stream>>>(em, lens, trans, head, last, ws, out);
}

// Round 11
// 617.895 us; speedup vs baseline: 1.1262x; 1.1262x over previous
//
#include <hip/hip_runtime.h>
#include <stdint.h>

#define T_LEN 2048
#define B_TOT 64
#define N_TAG 128

typedef __attribute__((ext_vector_type(4))) float f32x4;
typedef __attribute__((ext_vector_type(4))) uint32_t u32x4;
typedef __attribute__((ext_vector_type(2))) uint32_t u32x2;
typedef __attribute__((ext_vector_type(8))) int i32x8;

template <int S>
struct IC {
  static constexpr int value = S;
};

// pack two fp32 -> dword of two bf16 (round-half-up); elem0 in low half
__device__ __forceinline__ uint32_t pack2_bf16(float a, float b) {
  uint32_t ua = __float_as_uint(a) + 0x8000u;
  uint32_t ub = __float_as_uint(b) + 0x8000u;
  return __builtin_amdgcn_perm(ua, ub, 0x03020706u);
}
__device__ __forceinline__ float bf_lo(uint32_t w) {
  return __uint_as_float(w << 16);
}
__device__ __forceinline__ float bf_hi(uint32_t w) {
  return __uint_as_float(w & 0xffff0000u);
}
// pack 4 fp32 -> 4 fp8 e4m3 (OCP), bytes 0..3 = a,b,c,d
__device__ __forceinline__ uint32_t pack4_fp8(float a, float b, float c,
                                              float d) {
  int v = __builtin_amdgcn_cvt_pk_fp8_f32(a, b, 0, false);
  v = __builtin_amdgcn_cvt_pk_fp8_f32(c, d, v, true);
  return (uint32_t)v;
}
// pack 4 fp32 -> 4 bf8 e5m2 (OCP), bytes 0..3 = a,b,c,d
__device__ __forceinline__ uint32_t pack4_bf8(float a, float b, float c,
                                              float d) {
  int v = __builtin_amdgcn_cvt_pk_bf8_f32(a, b, 0, false);
  v = __builtin_amdgcn_cvt_pk_bf8_f32(c, d, v, true);
  return (uint32_t)v;
}

// Workgroup barrier draining ONLY lgkmcnt (LDS) -- the global eem prefetch
// stays in flight (step chain ~300 cyc < L3 latency; a vmcnt(0) drain would
// expose ~150 cyc/step). LDS producer->consumer ordering needs only lgkmcnt.
__device__ __forceinline__ void barrier_lds_only() {
  __asm__ volatile("s_waitcnt lgkmcnt(0)\n\ts_barrier" ::: "memory");
}

// prepass: ws[t][b][i] = bf16(exp(em[b][t][i])), i-pairs packed in u32
__global__ __launch_bounds__(256) void eem_prepass(const float* __restrict__ em,
                                                   uint32_t* __restrict__ ws) {
  const int tid = blockIdx.x * blockDim.x + threadIdx.x;  // 0 .. 2^21-1
  const int b = tid >> 15;
  const int rem = tid & 32767;
  const int t = rem >> 4;
  const int kk = rem & 15;  // 8 floats per thread
  const float4* src =
      (const float4*)(em + ((size_t)b * T_LEN + t) * N_TAG + kk * 8);
  const float4 p0 = src[0];
  const float4 p1 = src[1];
  u32x4 o;
  o[0] = pack2_bf16(__expf(p0.x), __expf(p0.y));
  o[1] = pack2_bf16(__expf(p0.z), __expf(p0.w));
  o[2] = pack2_bf16(__expf(p1.x), __expf(p1.y));
  o[3] = pack2_bf16(__expf(p1.z), __expf(p1.w));
  *(u32x4*)(ws + ((size_t)t * B_TOT + b) * (N_TAG / 2) + kk * 4) = o;
}

// 4 blocks x 512 threads (8 waves), 16 batches/block, 2 waves/SIMD.
// MX K=128 step: wave f owns j-tile [16f,16f+16) and does ONE
// mfma_scale_f32_16x16x128_f8f6f4 per step (A=E e4m3 cbsz=0, B=state bf8
// blgp=1, unit scales 0x7f7f7f7f) -- MFMA chain depth 4 -> 1. Standard
// layouts: A row m=lane&15 (j=16f+m), D row = 4q+r; k-byte map only needs
// A/B consistency (self-consistency argument, proven by R9/R10 fp8 rounds).
// State exchange: j-grouped LDS [batch][36 dwords] (pad -> write b32 2-way,
// read 2x b128 16B-aligned, conflict-free). Numerics = R10: damped probe
// controller (D=(e>>1)+3, 1-step lag, clamp +-40), state clamp 16384,
// exact L bookkeeping. lgkmcnt-only barrier keeps eem loads in flight.
__global__ __launch_bounds__(512, 2) void crf_fwd_kernel(
    const float* __restrict__ em, const int* __restrict__ lens,
    const float* __restrict__ trans, const float* __restrict__ head,
    const float* __restrict__ last, const uint32_t* __restrict__ eem,
    float* __restrict__ out) {
  const int lane = threadIdx.x & 63;
  const int w = threadIdx.x >> 6;  // wave id = j-tile f (0..7)
  const int c = lane & 15;         // batch-in-tile (D col / B col)
  const int q = lane >> 4;
  const int bg = (int)blockIdx.x * 16 + c;
  const int jb = 16 * w + 4 * q;  // lane's 4 j's: jb + r (D rows 4q+r)

  __shared__ uint32_t x_lds[2][16 * 36];  // [pingpong][batch*36 + jgroup]
  __shared__ int k_lds[16];               // per-batch scale exponent D
  __shared__ float cap_lds[8][16];

  // A operand (fp8 e4m3): lane (q, m=c) byte p=0..31 -> k = q*32+p,
  // A[m][k] = exp(trans[k][16w+c])   (j = 16w + m)
  i32x8 aop;
#pragma unroll
  for (int pd = 0; pd < 8; ++pd) {
    const int k0 = q * 32 + pd * 4;
    const int j = 16 * w + c;
    const float e0 = __expf(trans[(k0 + 0) * N_TAG + j]);
    const float e1 = __expf(trans[(k0 + 1) * N_TAG + j]);
    const float e2 = __expf(trans[(k0 + 2) * N_TAG + j]);
    const float e3 = __expf(trans[(k0 + 3) * N_TAG + j]);
    aop[pd] = (int)pack4_fp8(e0, e1, e2, e3);
  }

  float lastx[4];
#pragma unroll
  for (int r = 0; r < 4; ++r) lastx[r] = __expf(last[jb + r]);

  const int len = lens[bg];
  float L = 0.f, Lcap = 0.f;

  // initial state: S0[b][j] = bf8(e^{head_j + em[b][0][j]}), j = jb + r
  const float* emb = em + (size_t)bg * T_LEN * N_TAG;
  float v0[4];
#pragma unroll
  for (int r = 0; r < 4; ++r) v0[r] = __expf(head[jb + r] + emb[jb + r]);
  x_lds[0][c * 36 + 4 * w + q] = pack4_bf8(v0[0], v0[1], v0[2], v0[3]);
  if (w == 0 && lane < 16) k_lds[lane] = 3;  // initial D
  if (len == 1) {  // edge (setup guarantees len>=1024; keep correct)
    float s = v0[0] * lastx[0] + v0[1] * lastx[1] + v0[2] * lastx[2] +
              v0[3] * lastx[3];
    s += __shfl_xor(s, 16);
    s += __shfl_xor(s, 32);
    if (q == 0) cap_lds[w][c] = s;
  }
  __syncthreads();
  if (len == 1 && w == 0 && lane < 16) {
    float s = 0.f;
#pragma unroll
    for (int u = 0; u < 8; ++u) s += cap_lds[u][c];
    out[bg] = __logf(s);
  }

  // eem prefetch: slot t&3 holds row t (this lane's 4 j's = u32x2 of bf16)
  const size_t eoff = (size_t)bg * 64 + 8 * w + 2 * q;
  u32x2 eslot[4];
  auto issue_eem = [&](auto sc, int row) {
    constexpr int S = decltype(sc)::value;
    eslot[S] = *(const u32x2*)(eem + (size_t)row * 4096 + eoff);
  };
  issue_eem(IC<1>{}, 1);
  issue_eem(IC<2>{}, 2);
  issue_eem(IC<3>{}, 3);

  const f32x4 vzero = {0.f, 0.f, 0.f, 0.f};

  auto step = [&](auto slotc, int t) {
    constexpr int SLOT = decltype(slotc)::value;
    constexpr int RP = (SLOT + 1) & 1;  // read buffer (state of t-1)
    constexpr int WP = SLOT & 1;        // write buffer
    // prefetch first (global load gets max time in flight)
    {
      int row = t + 3;
      if (row > T_LEN - 1) row = T_LEN - 1;
      issue_eem(IC<(SLOT + 3) & 3>{}, row);
    }
    const int D = k_lds[c];  // scale exponent (last step's probe)
    // B operand: full k=128 bf8 state, 2x ds_read_b128 (aligned, pad-safe)
    const u32x4 s0 = *(const u32x4*)&x_lds[RP][c * 36 + 8 * q];
    const u32x4 s1 = *(const u32x4*)&x_lds[RP][c * 36 + 8 * q + 4];
    // unpack eem, fold per-step rescale 2^-D
    const u32x2 ev = eslot[SLOT];
    float ff[4];
    ff[0] = bf_lo(ev[0]);
    ff[1] = bf_hi(ev[0]);
    ff[2] = bf_lo(ev[1]);
    ff[3] = bf_hi(ev[1]);
    const float sc = __uint_as_float((uint32_t)(127 - D) << 23);
#pragma unroll
    for (int r = 0; r < 4; ++r) ff[r] *= sc;
    L += (float)D * 0.6931471805599453f;
    // ONE K=128 MX MFMA: A fp8 (cbsz=0), B bf8 (blgp=1), unit scales
    i32x8 bop;
    bop[0] = (int)s0[0];
    bop[1] = (int)s0[1];
    bop[2] = (int)s0[2];
    bop[3] = (int)s0[3];
    bop[4] = (int)s1[0];
    bop[5] = (int)s1[1];
    bop[6] = (int)s1[2];
    bop[7] = (int)s1[3];
    const f32x4 acc = __builtin_amdgcn_mfma_scale_f32_16x16x128_f8f6f4(
        aop, bop, vzero, 0, 1, 0, 0x7f7f7f7f, 0, 0x7f7f7f7f);
    // next state values (pre-clamp reused for capture)
    float st[4];
#pragma unroll
    for (int r = 0; r < 4; ++r) st[r] = acc[r] * ff[r];
    // capture: out_b = log(sum_j acc*eem*e^{last}) + L (this lane's 4 j's)
    if (t == len - 1) {
      float s = st[0] * lastx[0] + st[1] * lastx[1] + st[2] * lastx[2] +
                st[3] * lastx[3];
      s += __shfl_xor(s, 16);
      s += __shfl_xor(s, 32);
      if (q == 0) cap_lds[w][c] = s;
      Lcap = L;
    }
    // damped probe of j=0: wave 0, lanes 0-15 (q=0,r=0) hold alpha[0][c]
    if (w == 0 && lane < 16) {
      int e = (int)(__float_as_uint(acc[0]) >> 23) - 127;
      e = e < -40 ? -40 : (e > 40 ? 40 : e);
      k_lds[c] = (e >> 1) + 3;  // half-gain -> z^2 = z - 1/2, damped
    }
    // clamp (bf8-safe) and pack into j-group slot (4 j's per dword)
#pragma unroll
    for (int r = 0; r < 4; ++r) st[r] = fminf(st[r], 16384.f);
    x_lds[WP][c * 36 + 4 * w + q] = pack4_bf8(st[0], st[1], st[2], st[3]);
    barrier_lds_only();
    if (t == len - 1 && w == 0 && lane < 16) {
      float s = 0.f;
#pragma unroll
      for (int u = 0; u < 8; ++u) s += cap_lds[u][c];
      out[bg] = __logf(s) + Lcap;
    }
  };

  int t = 1;
#pragma unroll 1
  for (int it = 0; it < 511; ++it) {  // t = 1 .. 2044
    step(IC<1>{}, t);
    step(IC<2>{}, t + 1);
    step(IC<3>{}, t + 2);
    step(IC<0>{}, t + 3);
    t += 4;
  }
  step(IC<1>{}, t);      // 2045
  step(IC<2>{}, t + 1);  // 2046
  step(IC<3>{}, t + 2);  // 2047
}

extern "C" void kernel_launch(void* const* d_in, const int* in_sizes, int n_in,
                              void* d_out, int out_size, void* d_ws,
                              size_t ws_size, hipStream_t stream) {
  const float* em = (const float*)d_in[0];
  const int* lens = (const int*)d_in[1];
  const float* trans = (const float*)d_in[2];
  const float* head = (const float*)d_in[3];
  const float* last = (const float*)d_in[4];
  float* out = (float*)d_out;
  uint32_t* ws = (uint32_t*)d_ws;  // 2048*64*128 bf16 = 32 MiB

  eem_prepass<<<8192, 256, 0, stream>>>(em, ws);
  crf_fwd_kernel<<<4, 512, 0, stream>>>(em, lens, trans, head, last, ws, out);
}